// Round 9
// baseline (157.469 us; speedup 1.0000x reference)
//
#include <hip/hip_runtime.h>
#include <math.h>

#define N_NODES 10000
#define N_EDGES 160000
#define IN_FEATS 512
#define HEADS 8
#define OUT_FEATS 64
#define HF 512                   // HEADS*OUT_FEATS
#define NEG_SLOPE 0.2f
#define M_PAD 10048              // 157 * 64

typedef float  f32x4  __attribute__((ext_vector_type(4)));
typedef __bf16 bf16x8 __attribute__((ext_vector_type(8)));
typedef short  s16x8  __attribute__((ext_vector_type(8)));

__device__ __forceinline__ unsigned short f2bf_rn(float x) {
    unsigned u = __float_as_uint(x);
    unsigned r = u + 0x7FFFu + ((u >> 16) & 1u);
    return (unsigned short)(r >> 16);
}

__device__ __forceinline__ void gl_lds16(const void* g, void* l) {
    __builtin_amdgcn_global_load_lds((const __attribute__((address_space(1))) void*)g,
                                     (__attribute__((address_space(3))) void*)l, 16, 0, 0);
}

// ---- kernel 1: prep = feat->bf16(RN) + W transpose/round + dst histogram ----
#define SF_BLOCKS 5024           // M_PAD*IN_FEATS/4/256
#define PW_BLOCKS 64
#define HIST_BLOCKS 625
__global__ __launch_bounds__(256) void prep_kernel(const float* __restrict__ feat,
                                                   const float* __restrict__ W,
                                                   const int* __restrict__ dst,
                                                   unsigned short* __restrict__ Abf,
                                                   unsigned short* __restrict__ Bt,
                                                   int* __restrict__ counts) {
    __shared__ float tile[64][65];
    const int bid = blockIdx.x;
    const int tid = threadIdx.x;

    if (bid < SF_BLOCKS) {
        const int idx = bid * 256 + tid;         // one float4 per thread
        const int row = idx >> 7;
        const int c4  = idx & 127;
        float4 v = make_float4(0.f, 0.f, 0.f, 0.f);
        if (row < N_NODES)
            v = *reinterpret_cast<const float4*>(feat + (size_t)row * IN_FEATS + c4 * 4);
        ushort4 o;
        o.x = f2bf_rn(v.x);
        o.y = f2bf_rn(v.y);
        o.z = f2bf_rn(v.z);
        o.w = f2bf_rn(v.w);
        *reinterpret_cast<ushort4*>(Abf + (size_t)row * IN_FEATS + c4 * 4) = o;
    } else if (bid < SF_BLOCKS + PW_BLOCKS) {
        const int b2 = bid - SF_BLOCKS;
        const int k0 = (b2 & 7) * 64;
        const int n0 = (b2 >> 3) * 64;
        #pragma unroll
        for (int i = 0; i < 4; ++i) {
            int f = tid + 256 * i;
            int r = f >> 4, c4 = f & 15;
            float4 v = *reinterpret_cast<const float4*>(W + (size_t)(k0 + r) * HF + n0 + c4 * 4);
            tile[r][c4 * 4 + 0] = v.x;
            tile[r][c4 * 4 + 1] = v.y;
            tile[r][c4 * 4 + 2] = v.z;
            tile[r][c4 * 4 + 3] = v.w;
        }
        __syncthreads();
        #pragma unroll
        for (int i = 0; i < 4; ++i) {
            int f = tid + 256 * i;
            int rn = f >> 4, c4 = f & 15;
            ushort4 o;
            o.x = f2bf_rn(tile[c4 * 4 + 0][rn]);
            o.y = f2bf_rn(tile[c4 * 4 + 1][rn]);
            o.z = f2bf_rn(tile[c4 * 4 + 2][rn]);
            o.w = f2bf_rn(tile[c4 * 4 + 3][rn]);
            *reinterpret_cast<ushort4*>(Bt + (size_t)(n0 + rn) * IN_FEATS + k0 + c4 * 4) = o;
        }
    } else {
        const int e = (bid - SF_BLOCKS - PW_BLOCKS) * 256 + tid;
        if (e < N_EDGES) atomicAdd(&counts[dst[e]], 1);   // int atomic: native, fast
    }
}

// ---- kernel 2: persistent-B GEMM + fused el/er + scan (block 0) ----
// block b>0: head hh=(b-1)&7, rows rb=(b-1)>>3. B-panel (64 cols x 512 k, 64 KB)
// staged ONCE into LDS with XOR swizzle; A frags preloaded to registers; the
// K-loop has NO barriers. Wave w owns rows row0+w*16..+16 and the full head.
#define GTM 64
__global__ __launch_bounds__(256) void gemm_mfma(const unsigned short* __restrict__ Abf,
                                                 const unsigned short* __restrict__ Bt,
                                                 const float* __restrict__ attn_l,
                                                 const float* __restrict__ attn_r,
                                                 unsigned short* __restrict__ hbf,
                                                 float* __restrict__ el,
                                                 float* __restrict__ er,
                                                 const int* __restrict__ counts,
                                                 int* __restrict__ row_ptr,
                                                 int* __restrict__ cursor) {
    __shared__ unsigned short sB[64 * 512];   // 64 KB

    const int tid  = threadIdx.x;

    if (blockIdx.x == 0) {
        // ---- scan section: 256 threads x 40 elems; also zero cursor ----
        int* wb = (int*)sB;
        const int lane = tid & 63, wid = tid >> 6;
        for (int i = tid; i < N_NODES; i += 256) cursor[i] = 0;
        int loc[40];
        int tot = 0;
        #pragma unroll
        for (int j = 0; j < 40; ++j) {
            int idx = tid * 40 + j;
            int c = (idx < N_NODES) ? counts[idx] : 0;
            loc[j] = tot;
            tot += c;
        }
        int inc = tot;
        #pragma unroll
        for (int off = 1; off < 64; off <<= 1) {
            int nb = __shfl_up(inc, off);
            if (lane >= off) inc += nb;
        }
        if (lane == 63) wb[wid] = inc;
        __syncthreads();
        if (tid == 0) {
            int r = 0;
            #pragma unroll
            for (int i = 0; i < 4; ++i) { int x = wb[i]; wb[i] = r; r += x; }
        }
        __syncthreads();
        const int base = wb[wid] + inc - tot;
        #pragma unroll
        for (int j = 0; j < 40; ++j) {
            int idx = tid * 40 + j;
            if (idx < N_NODES) row_ptr[idx] = base + loc[j];
        }
        if (tid == 255) row_ptr[N_NODES] = base + tot;
        return;
    }

    const int b    = blockIdx.x - 1;
    const int hh   = b & 7;
    const int row0 = (b >> 3) * GTM;
    const int lane = tid & 63;
    const int w    = tid >> 6;
    const int m16  = lane & 15, quad = lane >> 4;
    const int col0 = hh * 64;

    // --- A preload: wave w rows row0+w*16..+16; all 16 k-tiles to registers ---
    const int arow = row0 + w * 16 + m16;
    const unsigned short* ab = Abf + (size_t)arow * IN_FEATS + quad * 8;
    s16x8 fa[16];
    #pragma unroll
    for (int kt = 0; kt < 16; ++kt)
        fa[kt] = *reinterpret_cast<const s16x8*>(ab + kt * 32);

    // --- B panel staging: 64 cols x 64 units(16B); unit u of col c stored at
    //     LDS unit c*64 + (u ^ (c&7)). Each wave stages cols w*16..+16. ---
    #pragma unroll
    for (int it = 0; it < 16; ++it) {
        const int c = w * 16 + it;                       // uniform per instr
        const int u = lane ^ (c & 7);                    // permuted source unit
        gl_lds16(Bt + (size_t)(col0 + c) * IN_FEATS + u * 8, sB + c * 512);
    }
    __syncthreads();

    // --- barrier-free K-loop: 16 x (4 ds_read_b128 + 4 MFMA) ---
    f32x4 acc[4] = {};
    #pragma unroll
    for (int kt = 0; kt < 16; ++kt) {
        s16x8 fb[4];
        #pragma unroll
        for (int ni = 0; ni < 4; ++ni) {
            const int c = ni * 16 + m16;
            const int v = (kt * 4 + quad) ^ (c & 7);
            fb[ni] = *reinterpret_cast<const s16x8*>(sB + c * 512 + v * 8);
        }
        #pragma unroll
        for (int ni = 0; ni < 4; ++ni)
            acc[ni] = __builtin_amdgcn_mfma_f32_16x16x32_bf16(
                __builtin_bit_cast(bf16x8, fa[kt]), __builtin_bit_cast(bf16x8, fb[ni]),
                acc[ni], 0, 0, 0);
    }

    // --- epilogue: C/D row = quad*4 + r, col = ni*16 + m16; wave owns full head ---
    float alw[4], arw[4];
    #pragma unroll
    for (int ni = 0; ni < 4; ++ni) {
        alw[ni] = attn_l[hh * OUT_FEATS + ni * 16 + m16];
        arw[ni] = attn_r[hh * OUT_FEATS + ni * 16 + m16];
    }
    #pragma unroll
    for (int r = 0; r < 4; ++r) {
        const int row = row0 + w * 16 + quad * 4 + r;
        if (row < N_NODES) {
            float pl = 0.f, pr = 0.f;
            #pragma unroll
            for (int ni = 0; ni < 4; ++ni) {
                const float v = acc[ni][r];
                hbf[(size_t)row * HF + hh * OUT_FEATS + ni * 16 + m16] = f2bf_rn(v);
                pl = fmaf(v, alw[ni], pl);
                pr = fmaf(v, arw[ni], pr);
            }
            #pragma unroll
            for (int off = 1; off < 16; off <<= 1) {
                pl += __shfl_xor(pl, off);
                pr += __shfl_xor(pr, off);
            }
            if (m16 == 0) {
                el[row * HEADS + hh] = pl;
                er[row * HEADS + hh] = pr;
            }
        }
    }
}

// ---- kernel 3: CSR scatter + per-edge alpha (no max subtraction) ----
// softmax is shift-invariant; logits are O(1..10) so exp() is safe without
// the segment-max pass. p = exp(leaky(el[src]+er[dst])) stored CSR-ordered.
__global__ __launch_bounds__(256) void scatter_alpha(const int* __restrict__ src,
                                                     const int* __restrict__ dst,
                                                     const int* __restrict__ row_ptr,
                                                     int* __restrict__ cursor,
                                                     const float* __restrict__ el,
                                                     const float* __restrict__ er,
                                                     int* __restrict__ ssrc,
                                                     float* __restrict__ palpha) {
    const int e = blockIdx.x * 256 + threadIdx.x;
    if (e >= N_EDGES) return;
    const int d  = dst[e];
    const int sn = src[e];
    const int pos = row_ptr[d] + atomicAdd(&cursor[d], 1);
    ssrc[pos] = sn;

    float4 l0 = *reinterpret_cast<const float4*>(el + sn * 8);
    float4 l1 = *reinterpret_cast<const float4*>(el + sn * 8 + 4);
    float4 r0 = *reinterpret_cast<const float4*>(er + d * 8);
    float4 r1 = *reinterpret_cast<const float4*>(er + d * 8 + 4);
    float x[8] = {l0.x + r0.x, l0.y + r0.y, l0.z + r0.z, l0.w + r0.w,
                  l1.x + r1.x, l1.y + r1.y, l1.z + r1.z, l1.w + r1.w};
    float p[8];
    #pragma unroll
    for (int h = 0; h < 8; ++h) {
        float v = x[h] > 0.f ? x[h] : NEG_SLOPE * x[h];
        p[h] = __expf(v);
    }
    *reinterpret_cast<float4*>(palpha + (size_t)pos * 8)     = make_float4(p[0], p[1], p[2], p[3]);
    *reinterpret_cast<float4*>(palpha + (size_t)pos * 8 + 4) = make_float4(p[4], p[5], p[6], p[7]);
}

// ---- kernel 4: wide aggregation; one wave per node; no LDS, no shuffles ----
__global__ __launch_bounds__(256) void aggregate_kernel(const unsigned short* __restrict__ hbf,
                                                        const float* __restrict__ palpha,
                                                        const float* __restrict__ bias,
                                                        const int* __restrict__ row_ptr,
                                                        const int* __restrict__ ssrc,
                                                        float* __restrict__ out) {
    const int n    = (blockIdx.x * 256 + threadIdx.x) >> 6;
    const int lane = threadIdx.x & 63;
    if (n >= N_NODES) return;
    const int head = lane >> 3;
    const int beg = row_ptr[n];
    const int deg = row_ptr[n + 1] - beg;

    float4 b0 = *reinterpret_cast<const float4*>(bias + lane * 8);
    float4 b1 = *reinterpret_cast<const float4*>(bias + lane * 8 + 4);
    float* op = out + (size_t)n * HF + lane * 8;
    if (deg == 0) {
        *reinterpret_cast<float4*>(op)     = b0;
        *reinterpret_cast<float4*>(op + 4) = b1;
        return;
    }

    const int*   __restrict__ sp = ssrc + beg;
    const float* __restrict__ ap = palpha + (size_t)beg * 8 + head;
    const unsigned short* __restrict__ hb = hbf + lane * 8;

    float acc[8] = {};
    float s = 0.f;

    for (int k = 0; k < deg; k += 8) {
        float a[8]; int sx[8];
        #pragma unroll
        for (int j = 0; j < 8; ++j) {
            const int kk = k + j;
            const int kc = (kk < deg) ? kk : 0;
            sx[j] = sp[kc];
            a[j]  = (kk < deg) ? ap[(size_t)kc * 8] : 0.f;
        }
        uint4 u[8];
        #pragma unroll
        for (int j = 0; j < 8; ++j)
            u[j] = *reinterpret_cast<const uint4*>(hb + (size_t)sx[j] * HF);
        #pragma unroll
        for (int j = 0; j < 8; ++j) {
            const unsigned* wp = (const unsigned*)&u[j];
            s += a[j];
            #pragma unroll
            for (int q = 0; q < 4; ++q) {
                acc[2 * q]     = fmaf(a[j], __uint_as_float(wp[q] << 16),         acc[2 * q]);
                acc[2 * q + 1] = fmaf(a[j], __uint_as_float(wp[q] & 0xFFFF0000u), acc[2 * q + 1]);
            }
        }
    }

    const float inv = 1.0f / s;
    float4 o0 = make_float4(acc[0] * inv + b0.x, acc[1] * inv + b0.y,
                            acc[2] * inv + b0.z, acc[3] * inv + b0.w);
    float4 o1 = make_float4(acc[4] * inv + b1.x, acc[5] * inv + b1.y,
                            acc[6] * inv + b1.z, acc[7] * inv + b1.w);
    *reinterpret_cast<float4*>(op)     = o0;
    *reinterpret_cast<float4*>(op + 4) = o1;
}

// ---- launch ----
extern "C" void kernel_launch(void* const* d_in, const int* in_sizes, int n_in,
                              void* d_out, int out_size, void* d_ws, size_t ws_size,
                              hipStream_t stream) {
    const float* feat   = (const float*)d_in[0];
    const float* W      = (const float*)d_in[1];
    const float* attn_l = (const float*)d_in[2];
    const float* attn_r = (const float*)d_in[3];
    const float* bias   = (const float*)d_in[4];
    const int*   src    = (const int*)d_in[5];
    const int*   dst    = (const int*)d_in[6];
    float* out = (float*)d_out;

    char* ws = (char*)d_ws;
    unsigned short* Abf    = (unsigned short*)ws; ws += (size_t)M_PAD * IN_FEATS * 2;   // 10.29 MB
    unsigned short* Bt     = (unsigned short*)ws; ws += (size_t)IN_FEATS * HF * 2;      // 0.52 MB
    unsigned short* hbf    = (unsigned short*)ws; ws += (size_t)N_NODES * HF * 2;       // 10.24 MB
    float*          el_buf = (float*)ws;          ws += (size_t)N_NODES * HEADS * 4;
    float*          er_buf = (float*)ws;          ws += (size_t)N_NODES * HEADS * 4;
    float*          palpha = (float*)ws;          ws += (size_t)N_EDGES * HEADS * 4;    // 5.12 MB
    int*            ssrc   = (int*)ws;            ws += (size_t)N_EDGES * 4;
    int*            counts = (int*)ws;            ws += (size_t)N_NODES * 4;
    int*            cursor = (int*)ws;            ws += (size_t)N_NODES * 4;
    int*            row_ptr= (int*)ws;            ws += (size_t)(N_NODES + 1) * 4;

    // 1) zero hist counts (async memset, graph-capturable)
    hipMemsetAsync(counts, 0, (size_t)N_NODES * 4, stream);

    // 2) prep: feat->bf16, W transpose->bf16, dst histogram
    prep_kernel<<<SF_BLOCKS + PW_BLOCKS + HIST_BLOCKS, 256, 0, stream>>>(
        feat, W, dst, Abf, Bt, counts);

    // 3) persistent-B GEMM + fused el/er + bf16 h; block 0 = scan + cursor zero
    gemm_mfma<<<1 + 8 * (M_PAD / GTM), 256, 0, stream>>>(
        Abf, Bt, attn_l, attn_r, hbf, el_buf, er_buf, counts, row_ptr, cursor);

    // 4) CSR scatter + per-edge un-normalized alpha
    scatter_alpha<<<(N_EDGES + 255) / 256, 256, 0, stream>>>(
        src, dst, row_ptr, cursor, el_buf, er_buf, ssrc, palpha);

    // 5) wide aggregation (+bias), denominator folded into the fma loop
    aggregate_kernel<<<(N_NODES * 64 + 255) / 256, 256, 0, stream>>>(
        hbf, palpha, bias, row_ptr, ssrc, out);
}

// Round 10
// 157.324 us; speedup vs baseline: 1.0009x; 1.0009x over previous
//
#include <hip/hip_runtime.h>
#include <math.h>

#define N_NODES 10000
#define N_EDGES 160000
#define IN_FEATS 512
#define HEADS 8
#define OUT_FEATS 64
#define HF 512                   // HEADS*OUT_FEATS
#define NEG_SLOPE 0.2f
#define M_PAD 10048              // 157 * 64

typedef float  f32x4  __attribute__((ext_vector_type(4)));
typedef __bf16 bf16x8 __attribute__((ext_vector_type(8)));
typedef short  s16x8  __attribute__((ext_vector_type(8)));

__device__ __forceinline__ unsigned short f2bf_rn(float x) {
    unsigned u = __float_as_uint(x);
    unsigned r = u + 0x7FFFu + ((u >> 16) & 1u);
    return (unsigned short)(r >> 16);
}

__device__ __forceinline__ void gl_lds16(const void* g, void* l) {
    __builtin_amdgcn_global_load_lds((const __attribute__((address_space(1))) void*)g,
                                     (__attribute__((address_space(3))) void*)l, 16, 0, 0);
}

// ---- kernel 1: prep = feat->bf16(RN) + W transpose/round + dst histogram ----
#define SF_BLOCKS 5024           // M_PAD*IN_FEATS/4/256
#define PW_BLOCKS 64
#define HIST_BLOCKS 625
__global__ __launch_bounds__(256) void prep_kernel(const float* __restrict__ feat,
                                                   const float* __restrict__ W,
                                                   const int* __restrict__ dst,
                                                   unsigned short* __restrict__ Abf,
                                                   unsigned short* __restrict__ Bt,
                                                   int* __restrict__ counts) {
    __shared__ float tile[64][65];
    const int bid = blockIdx.x;
    const int tid = threadIdx.x;

    if (bid < SF_BLOCKS) {
        const int idx = bid * 256 + tid;         // one float4 per thread
        const int row = idx >> 7;
        const int c4  = idx & 127;
        float4 v = make_float4(0.f, 0.f, 0.f, 0.f);
        if (row < N_NODES)
            v = *reinterpret_cast<const float4*>(feat + (size_t)row * IN_FEATS + c4 * 4);
        ushort4 o;
        o.x = f2bf_rn(v.x);
        o.y = f2bf_rn(v.y);
        o.z = f2bf_rn(v.z);
        o.w = f2bf_rn(v.w);
        *reinterpret_cast<ushort4*>(Abf + (size_t)row * IN_FEATS + c4 * 4) = o;
    } else if (bid < SF_BLOCKS + PW_BLOCKS) {
        const int b2 = bid - SF_BLOCKS;
        const int k0 = (b2 & 7) * 64;
        const int n0 = (b2 >> 3) * 64;
        #pragma unroll
        for (int i = 0; i < 4; ++i) {
            int f = tid + 256 * i;
            int r = f >> 4, c4 = f & 15;
            float4 v = *reinterpret_cast<const float4*>(W + (size_t)(k0 + r) * HF + n0 + c4 * 4);
            tile[r][c4 * 4 + 0] = v.x;
            tile[r][c4 * 4 + 1] = v.y;
            tile[r][c4 * 4 + 2] = v.z;
            tile[r][c4 * 4 + 3] = v.w;
        }
        __syncthreads();
        #pragma unroll
        for (int i = 0; i < 4; ++i) {
            int f = tid + 256 * i;
            int rn = f >> 4, c4 = f & 15;
            ushort4 o;
            o.x = f2bf_rn(tile[c4 * 4 + 0][rn]);
            o.y = f2bf_rn(tile[c4 * 4 + 1][rn]);
            o.z = f2bf_rn(tile[c4 * 4 + 2][rn]);
            o.w = f2bf_rn(tile[c4 * 4 + 3][rn]);
            *reinterpret_cast<ushort4*>(Bt + (size_t)(n0 + rn) * IN_FEATS + k0 + c4 * 4) = o;
        }
    } else {
        const int e = (bid - SF_BLOCKS - PW_BLOCKS) * 256 + tid;
        if (e < N_EDGES) atomicAdd(&counts[dst[e]], 1);   // int atomic: native, fast
    }
}

// ---- kernel 2: persistent-B GEMM + fused el/er + scan (block 0) ----
#define GTM 64
__global__ __launch_bounds__(256) void gemm_mfma(const unsigned short* __restrict__ Abf,
                                                 const unsigned short* __restrict__ Bt,
                                                 const float* __restrict__ attn_l,
                                                 const float* __restrict__ attn_r,
                                                 unsigned short* __restrict__ hbf,
                                                 float* __restrict__ el,
                                                 float* __restrict__ er,
                                                 const int* __restrict__ counts,
                                                 int* __restrict__ row_ptr,
                                                 int* __restrict__ cursor) {
    __shared__ unsigned short sB[64 * 512];   // 64 KB

    const int tid  = threadIdx.x;

    if (blockIdx.x == 0) {
        // ---- scan section: 256 threads x 40 elems; also zero cursor ----
        int* wb = (int*)sB;
        const int lane = tid & 63, wid = tid >> 6;
        for (int i = tid; i < N_NODES; i += 256) cursor[i] = 0;
        int loc[40];
        int tot = 0;
        #pragma unroll
        for (int j = 0; j < 40; ++j) {
            int idx = tid * 40 + j;
            int c = (idx < N_NODES) ? counts[idx] : 0;
            loc[j] = tot;
            tot += c;
        }
        int inc = tot;
        #pragma unroll
        for (int off = 1; off < 64; off <<= 1) {
            int nb = __shfl_up(inc, off);
            if (lane >= off) inc += nb;
        }
        if (lane == 63) wb[wid] = inc;
        __syncthreads();
        if (tid == 0) {
            int r = 0;
            #pragma unroll
            for (int i = 0; i < 4; ++i) { int x = wb[i]; wb[i] = r; r += x; }
        }
        __syncthreads();
        const int base = wb[wid] + inc - tot;
        #pragma unroll
        for (int j = 0; j < 40; ++j) {
            int idx = tid * 40 + j;
            if (idx < N_NODES) row_ptr[idx] = base + loc[j];
        }
        if (tid == 255) row_ptr[N_NODES] = base + tot;
        return;
    }

    const int b    = blockIdx.x - 1;
    const int hh   = b & 7;
    const int row0 = (b >> 3) * GTM;
    const int lane = tid & 63;
    const int w    = tid >> 6;
    const int m16  = lane & 15, quad = lane >> 4;
    const int col0 = hh * 64;

    // --- A preload: wave w rows row0+w*16..+16; all 16 k-tiles to registers ---
    const int arow = row0 + w * 16 + m16;
    const unsigned short* ab = Abf + (size_t)arow * IN_FEATS + quad * 8;
    s16x8 fa[16];
    #pragma unroll
    for (int kt = 0; kt < 16; ++kt)
        fa[kt] = *reinterpret_cast<const s16x8*>(ab + kt * 32);

    // --- B panel staging: unit u of col c stored at LDS unit c*64 + (u^(c&7)) ---
    #pragma unroll
    for (int it = 0; it < 16; ++it) {
        const int c = w * 16 + it;
        const int u = lane ^ (c & 7);
        gl_lds16(Bt + (size_t)(col0 + c) * IN_FEATS + u * 8, sB + c * 512);
    }
    __syncthreads();

    // --- barrier-free K-loop: 16 x (4 ds_read_b128 + 4 MFMA) ---
    f32x4 acc[4] = {};
    #pragma unroll
    for (int kt = 0; kt < 16; ++kt) {
        s16x8 fb[4];
        #pragma unroll
        for (int ni = 0; ni < 4; ++ni) {
            const int c = ni * 16 + m16;
            const int v = (kt * 4 + quad) ^ (c & 7);
            fb[ni] = *reinterpret_cast<const s16x8*>(sB + c * 512 + v * 8);
        }
        #pragma unroll
        for (int ni = 0; ni < 4; ++ni)
            acc[ni] = __builtin_amdgcn_mfma_f32_16x16x32_bf16(
                __builtin_bit_cast(bf16x8, fa[kt]), __builtin_bit_cast(bf16x8, fb[ni]),
                acc[ni], 0, 0, 0);
    }

    // --- epilogue ---
    float alw[4], arw[4];
    #pragma unroll
    for (int ni = 0; ni < 4; ++ni) {
        alw[ni] = attn_l[hh * OUT_FEATS + ni * 16 + m16];
        arw[ni] = attn_r[hh * OUT_FEATS + ni * 16 + m16];
    }
    #pragma unroll
    for (int r = 0; r < 4; ++r) {
        const int row = row0 + w * 16 + quad * 4 + r;
        if (row < N_NODES) {
            float pl = 0.f, pr = 0.f;
            #pragma unroll
            for (int ni = 0; ni < 4; ++ni) {
                const float v = acc[ni][r];
                hbf[(size_t)row * HF + hh * OUT_FEATS + ni * 16 + m16] = f2bf_rn(v);
                pl = fmaf(v, alw[ni], pl);
                pr = fmaf(v, arw[ni], pr);
            }
            #pragma unroll
            for (int off = 1; off < 16; off <<= 1) {
                pl += __shfl_xor(pl, off);
                pr += __shfl_xor(pr, off);
            }
            if (m16 == 0) {
                el[row * HEADS + hh] = pl;
                er[row * HEADS + hh] = pr;
            }
        }
    }
}

// ---- kernel 3: CSR scatter + per-edge alpha (no max subtraction) ----
__global__ __launch_bounds__(256) void scatter_alpha(const int* __restrict__ src,
                                                     const int* __restrict__ dst,
                                                     const int* __restrict__ row_ptr,
                                                     int* __restrict__ cursor,
                                                     const float* __restrict__ el,
                                                     const float* __restrict__ er,
                                                     int* __restrict__ ssrc,
                                                     float* __restrict__ palpha) {
    const int e = blockIdx.x * 256 + threadIdx.x;
    if (e >= N_EDGES) return;
    const int d  = dst[e];
    const int sn = src[e];
    const int pos = row_ptr[d] + atomicAdd(&cursor[d], 1);
    ssrc[pos] = sn;

    float4 l0 = *reinterpret_cast<const float4*>(el + sn * 8);
    float4 l1 = *reinterpret_cast<const float4*>(el + sn * 8 + 4);
    float4 r0 = *reinterpret_cast<const float4*>(er + d * 8);
    float4 r1 = *reinterpret_cast<const float4*>(er + d * 8 + 4);
    float x[8] = {l0.x + r0.x, l0.y + r0.y, l0.z + r0.z, l0.w + r0.w,
                  l1.x + r1.x, l1.y + r1.y, l1.z + r1.z, l1.w + r1.w};
    float p[8];
    #pragma unroll
    for (int h = 0; h < 8; ++h) {
        float v = x[h] > 0.f ? x[h] : NEG_SLOPE * x[h];
        p[h] = __expf(v);
    }
    *reinterpret_cast<float4*>(palpha + (size_t)pos * 8)     = make_float4(p[0], p[1], p[2], p[3]);
    *reinterpret_cast<float4*>(palpha + (size_t)pos * 8 + 4) = make_float4(p[4], p[5], p[6], p[7]);
}

// ---- kernel 4: wide aggregation; one BLOCK per node, 4 waves split edges ----
// wave w handles edge batches [w*8, +8) stride 32; lane owns 8 feats of head
// lane>>3; partial acc/s reduced across waves via stride-9 LDS (conflict-free).
__global__ __launch_bounds__(256) void aggregate_kernel(const unsigned short* __restrict__ hbf,
                                                        const float* __restrict__ palpha,
                                                        const float* __restrict__ bias,
                                                        const int* __restrict__ row_ptr,
                                                        const int* __restrict__ ssrc,
                                                        float* __restrict__ out) {
    __shared__ float red[4][64 * 9];
    const int n    = blockIdx.x;
    const int w    = threadIdx.x >> 6;
    const int lane = threadIdx.x & 63;
    const int head = lane >> 3;
    const int beg = row_ptr[n];
    const int deg = row_ptr[n + 1] - beg;

    const int*   __restrict__ sp = ssrc + beg;
    const float* __restrict__ ap = palpha + (size_t)beg * 8 + head;
    const unsigned short* __restrict__ hb = hbf + lane * 8;

    float acc[8] = {};
    float s = 0.f;

    for (int k = w * 8; k < deg; k += 32) {
        float a[8]; int sx[8];
        #pragma unroll
        for (int j = 0; j < 8; ++j) {
            const int kk = k + j;
            const int kc = (kk < deg) ? kk : 0;
            sx[j] = sp[kc];
            a[j]  = (kk < deg) ? ap[(size_t)kc * 8] : 0.f;
        }
        uint4 u[8];
        #pragma unroll
        for (int j = 0; j < 8; ++j)
            u[j] = *reinterpret_cast<const uint4*>(hb + (size_t)sx[j] * HF);
        #pragma unroll
        for (int j = 0; j < 8; ++j) {
            const unsigned* wp = (const unsigned*)&u[j];
            s += a[j];
            #pragma unroll
            for (int q = 0; q < 4; ++q) {
                acc[2 * q]     = fmaf(a[j], __uint_as_float(wp[q] << 16),         acc[2 * q]);
                acc[2 * q + 1] = fmaf(a[j], __uint_as_float(wp[q] & 0xFFFF0000u), acc[2 * q + 1]);
            }
        }
    }

    // cross-wave reduction
    float* rp = &red[w][lane * 9];
    #pragma unroll
    for (int q = 0; q < 8; ++q) rp[q] = acc[q];
    rp[8] = s;
    __syncthreads();
    if (w == 0) {
        #pragma unroll
        for (int v = 1; v < 4; ++v) {
            const float* qp = &red[v][lane * 9];
            #pragma unroll
            for (int q = 0; q < 8; ++q) acc[q] += qp[q];
            s += qp[8];
        }
        const float inv = (deg > 0) ? 1.0f / s : 0.f;
        float4 b0 = *reinterpret_cast<const float4*>(bias + lane * 8);
        float4 b1 = *reinterpret_cast<const float4*>(bias + lane * 8 + 4);
        float* op = out + (size_t)n * HF + lane * 8;
        float4 o0 = make_float4(acc[0] * inv + b0.x, acc[1] * inv + b0.y,
                                acc[2] * inv + b0.z, acc[3] * inv + b0.w);
        float4 o1 = make_float4(acc[4] * inv + b1.x, acc[5] * inv + b1.y,
                                acc[6] * inv + b1.z, acc[7] * inv + b1.w);
        *reinterpret_cast<float4*>(op)     = o0;
        *reinterpret_cast<float4*>(op + 4) = o1;
    }
}

// ---- launch ----
extern "C" void kernel_launch(void* const* d_in, const int* in_sizes, int n_in,
                              void* d_out, int out_size, void* d_ws, size_t ws_size,
                              hipStream_t stream) {
    const float* feat   = (const float*)d_in[0];
    const float* W      = (const float*)d_in[1];
    const float* attn_l = (const float*)d_in[2];
    const float* attn_r = (const float*)d_in[3];
    const float* bias   = (const float*)d_in[4];
    const int*   src    = (const int*)d_in[5];
    const int*   dst    = (const int*)d_in[6];
    float* out = (float*)d_out;

    char* ws = (char*)d_ws;
    unsigned short* Abf    = (unsigned short*)ws; ws += (size_t)M_PAD * IN_FEATS * 2;   // 10.29 MB
    unsigned short* Bt     = (unsigned short*)ws; ws += (size_t)IN_FEATS * HF * 2;      // 0.52 MB
    unsigned short* hbf    = (unsigned short*)ws; ws += (size_t)N_NODES * HF * 2;       // 10.24 MB
    float*          el_buf = (float*)ws;          ws += (size_t)N_NODES * HEADS * 4;
    float*          er_buf = (float*)ws;          ws += (size_t)N_NODES * HEADS * 4;
    float*          palpha = (float*)ws;          ws += (size_t)N_EDGES * HEADS * 4;    // 5.12 MB
    int*            ssrc   = (int*)ws;            ws += (size_t)N_EDGES * 4;
    int*            counts = (int*)ws;            ws += (size_t)N_NODES * 4;
    int*            cursor = (int*)ws;            ws += (size_t)N_NODES * 4;
    int*            row_ptr= (int*)ws;            ws += (size_t)(N_NODES + 1) * 4;

    // 1) zero hist counts (async memset, graph-capturable)
    hipMemsetAsync(counts, 0, (size_t)N_NODES * 4, stream);

    // 2) prep: feat->bf16, W transpose->bf16, dst histogram
    prep_kernel<<<SF_BLOCKS + PW_BLOCKS + HIST_BLOCKS, 256, 0, stream>>>(
        feat, W, dst, Abf, Bt, counts);

    // 3) persistent-B GEMM + fused el/er + bf16 h; block 0 = scan + cursor zero
    gemm_mfma<<<1 + 8 * (M_PAD / GTM), 256, 0, stream>>>(
        Abf, Bt, attn_l, attn_r, hbf, el_buf, er_buf, counts, row_ptr, cursor);

    // 4) CSR scatter + per-edge un-normalized alpha
    scatter_alpha<<<(N_EDGES + 255) / 256, 256, 0, stream>>>(
        src, dst, row_ptr, cursor, el_buf, er_buf, ssrc, palpha);

    // 5) wide aggregation (+bias): one block per node, 4 waves split the edges
    aggregate_kernel<<<N_NODES, 256, 0, stream>>>(
        hbf, palpha, bias, row_ptr, ssrc, out);
}